// Round 1
// baseline (180.369 us; speedup 1.0000x reference)
//
#include <hip/hip_runtime.h>

#define BATCH 262144
#define NI 9
#define NH 100
#define NO 2
#define T 25

// R11: packed-FP32 rewrite of R10. R10 sits at 3.05 cyc/VALU-instr, which
// equals the m07-measured chip VALU issue ceiling (103 TF) -> cyc/instr is
// done; only instruction COUNT is left. v_pk_fma_f32 (VOP3P, gfx90a+/gfx950)
// does 2 fp32 lane-ops per issue slot. Process h in pairs (h,h+1):
//   mem update / reset-subtract / threshold-scale : 3x v_pk_fma_f32
//   spike clamp                                   : 2x v_med3_f32 (no pk form)
//   acc (pair = (out0,out1))                      : 2x v_pk_fma_f32 with
//     op_sel splat of spk_h / spk_h' so the accumulation order stays exactly
//     h=0,1,...,49 per output -> BIT-IDENTICAL to R10's passing output.
// Per pair-iter ~205 VALU vs R10's 324 per 2h (0.63x; 0.68x after losing
// most of the never-spike skip, which coarsens to per-pair).
// Predicted: 164.5 -> ~115 us if pk issues at scalar rate; ~neutral if pk
// costs 2 slots. SQ_INSTS_VALU -35%.
// Per-lane math unchanged: mem=fma(.95,mem,c); mem=fma(spk,-1,mem);
// pre=fma(K,mem,-K), K=2^60; spk=med3(pre,0,1) == (mem>1)?1:0 exactly.
// Never-spike skip (exact 25-step bound): max(c_h,c_h') <= 0.0625 -> both
// provably spike-free -> skipping adds only exact +0.0 terms.

typedef float f32x2 __attribute__((ext_vector_type(2)));

#define TSTEP(t) \
  "v_pk_fma_f32 v[8:9], v[4:5], v[8:9], v[10:11]\n\t"                          \
  "v_pk_fma_f32 v[8:9], v[12:13], v[0:1], v[8:9]\n\t"                          \
  "v_pk_fma_f32 v[14:15], v[6:7], v[8:9], v[2:3]\n\t"                          \
  "v_med3_f32 v12, v14, 0, 1.0\n\t"                                            \
  "v_med3_f32 v13, v15, 0, 1.0\n\t"                                            \
  "v_pk_fma_f32 %[a" #t "], v[16:17], v[12:13], %[a" #t "] op_sel:[0,0,0] op_sel_hi:[1,0,1]\n\t" \
  "v_pk_fma_f32 %[a" #t "], v[18:19], v[12:13], %[a" #t "] op_sel:[0,1,0] op_sel_hi:[1,1,1]\n\t"

__global__
__attribute__((amdgpu_flat_work_group_size(256, 256), amdgpu_waves_per_eu(4, 8)))
void snn_fwd(
    const float* __restrict__ x,
    const float* __restrict__ W1,
    const float* __restrict__ b1,
    const float* __restrict__ W2,
    const float* __restrict__ b2,
    float* __restrict__ out)
{
    __shared__ f32x2 red[13 * 128];   // 13 t-slots x 128 elems = 13312 B

    const int tid  = threadIdx.x;
    const int lane = tid & 63;
    const int w    = tid >> 6;
    const int half = __builtin_amdgcn_readfirstlane(w & 1);  // wave-uniform
    const int el   = (w >> 1) * 64 + lane;                   // 0..127
    const int e    = blockIdx.x * 128 + el;

    float xi[NI];
#pragma unroll
    for (int i = 0; i < NI; ++i) xi[i] = x[(size_t)e * NI + i];

    f32x2 acc[T];
#pragma unroll
    for (int t = 0; t < T; ++t) { acc[t].x = 0.0f; acc[t].y = 0.0f; }

    // Uniform (SGPR) h-partition pointers. Each thread owns 50 h = 25 pairs.
    const float* W1h = W1 + half * 50 * NI;
    const float* b1h = b1 + half * 50;
    const float* W2h = W2 + half * 50;   // W2[1,h] at byte offset +0x190

    asm volatile(
        "s_mov_b64 s[40:41], %[pw1]\n\t"
        "s_mov_b64 s[42:43], %[pb1]\n\t"
        "s_mov_b64 s[44:45], %[pw2]\n\t"
        // constant pairs (hoisted; TSTEP is VGPR-only)
        "v_mov_b32 v0, 0xbf800000\n\t"    // -1.0
        "v_mov_b32 v1, 0xbf800000\n\t"
        "v_mov_b32 v2, 0xdd800000\n\t"    // -K = -2^60
        "v_mov_b32 v3, 0xdd800000\n\t"
        "v_mov_b32 v4, 0x3f733333\n\t"    // beta = 0.95
        "v_mov_b32 v5, 0x3f733333\n\t"
        "v_mov_b32 v6, 0x5d800000\n\t"    // K = 2^60
        "v_mov_b32 v7, 0x5d800000\n\t"
        "s_mov_b32 s46, 25\n\t"           // pair counter
        // first pair's weights: W1 rows h,h+1 are 18 contiguous dwords
        "s_load_dwordx16 s[48:63], s[40:41], 0x0\n\t"
        "s_load_dwordx2 s[64:65], s[40:41], 0x40\n\t"
        "s_load_dwordx2 s[66:67], s[42:43], 0x0\n\t"
        "s_load_dword s68, s[44:45], 0x0\n\t"      // W2[0,h]
        "s_load_dword s69, s[44:45], 0x190\n\t"    // W2[1,h]
        "s_load_dword s70, s[44:45], 0x4\n\t"      // W2[0,h+1]
        "s_load_dword s71, s[44:45], 0x194\n\t"    // W2[1,h+1]
        "1:\n\t"
        "s_waitcnt lgkmcnt(0)\n\t"
        "v_mov_b32 v16, s68\n\t"          // (w0_h, w1_h) pair
        "v_mov_b32 v17, s69\n\t"
        "v_mov_b32 v18, s70\n\t"          // (w0_h', w1_h') pair
        "v_mov_b32 v19, s71\n\t"
        // cur1 for h (-> v10) and h' (-> v11); identical op order to R10
        "v_mul_f32 v10, s48, %[x0]\n\t"
        "v_fma_f32 v10, s49, %[x1], v10\n\t"
        "v_fma_f32 v10, s50, %[x2], v10\n\t"
        "v_fma_f32 v10, s51, %[x3], v10\n\t"
        "v_fma_f32 v10, s52, %[x4], v10\n\t"
        "v_fma_f32 v10, s53, %[x5], v10\n\t"
        "v_fma_f32 v10, s54, %[x6], v10\n\t"
        "v_fma_f32 v10, s55, %[x7], v10\n\t"
        "v_fma_f32 v10, s56, %[x8], v10\n\t"
        "v_add_f32 v10, s66, v10\n\t"
        "v_mul_f32 v11, s57, %[x0]\n\t"
        "v_fma_f32 v11, s58, %[x1], v11\n\t"
        "v_fma_f32 v11, s59, %[x2], v11\n\t"
        "v_fma_f32 v11, s60, %[x3], v11\n\t"
        "v_fma_f32 v11, s61, %[x4], v11\n\t"
        "v_fma_f32 v11, s62, %[x5], v11\n\t"
        "v_fma_f32 v11, s63, %[x6], v11\n\t"
        "v_fma_f32 v11, s64, %[x7], v11\n\t"
        "v_fma_f32 v11, s65, %[x8], v11\n\t"
        "v_add_f32 v11, s67, v11\n\t"
        // prefetch next pair's weights (skip on last iteration)
        "s_cmp_lg_u32 s46, 1\n\t"
        "s_cbranch_scc0 2f\n\t"
        "s_add_u32 s40, s40, 72\n\t"
        "s_addc_u32 s41, s41, 0\n\t"
        "s_add_u32 s42, s42, 8\n\t"
        "s_addc_u32 s43, s43, 0\n\t"
        "s_add_u32 s44, s44, 8\n\t"
        "s_addc_u32 s45, s45, 0\n\t"
        "s_load_dwordx16 s[48:63], s[40:41], 0x0\n\t"
        "s_load_dwordx2 s[64:65], s[40:41], 0x40\n\t"
        "s_load_dwordx2 s[66:67], s[42:43], 0x0\n\t"
        "s_load_dword s68, s[44:45], 0x0\n\t"
        "s_load_dword s69, s[44:45], 0x190\n\t"
        "s_load_dword s70, s[44:45], 0x4\n\t"
        "s_load_dword s71, s[44:45], 0x194\n\t"
        "2:\n\t"
        // never-spike skip, pair-level: both halves must be provably dead
        "v_max_f32 v14, v10, v11\n\t"
        "v_cmp_lt_f32 vcc, 0x3d800000, v14\n\t"
        "s_cbranch_vccz 3f\n\t"
        "v_mov_b32 v8, 0\n\t"             // memP = 0
        "v_mov_b32 v9, 0\n\t"
        "v_mov_b32 v12, 0\n\t"            // spkP = 0
        "v_mov_b32 v13, 0\n\t"
        TSTEP(0)  TSTEP(1)  TSTEP(2)  TSTEP(3)  TSTEP(4)
        TSTEP(5)  TSTEP(6)  TSTEP(7)  TSTEP(8)  TSTEP(9)
        TSTEP(10) TSTEP(11) TSTEP(12) TSTEP(13) TSTEP(14)
        TSTEP(15) TSTEP(16) TSTEP(17) TSTEP(18) TSTEP(19)
        TSTEP(20) TSTEP(21) TSTEP(22) TSTEP(23) TSTEP(24)
        "3:\n\t"
        "s_sub_u32 s46, s46, 1\n\t"
        "s_cmp_lg_u32 s46, 0\n\t"
        "s_cbranch_scc1 1b\n\t"
        : [a0]"+v"(acc[0]),   [a1]"+v"(acc[1]),   [a2]"+v"(acc[2]),
          [a3]"+v"(acc[3]),   [a4]"+v"(acc[4]),   [a5]"+v"(acc[5]),
          [a6]"+v"(acc[6]),   [a7]"+v"(acc[7]),   [a8]"+v"(acc[8]),
          [a9]"+v"(acc[9]),   [a10]"+v"(acc[10]), [a11]"+v"(acc[11]),
          [a12]"+v"(acc[12]), [a13]"+v"(acc[13]), [a14]"+v"(acc[14]),
          [a15]"+v"(acc[15]), [a16]"+v"(acc[16]), [a17]"+v"(acc[17]),
          [a18]"+v"(acc[18]), [a19]"+v"(acc[19]), [a20]"+v"(acc[20]),
          [a21]"+v"(acc[21]), [a22]"+v"(acc[22]), [a23]"+v"(acc[23]),
          [a24]"+v"(acc[24])
        : [pw1]"s"(W1h), [pb1]"s"(b1h), [pw2]"s"(W2h),
          [x0]"v"(xi[0]), [x1]"v"(xi[1]), [x2]"v"(xi[2]), [x3]"v"(xi[3]),
          [x4]"v"(xi[4]), [x5]"v"(xi[5]), [x6]"v"(xi[6]), [x7]"v"(xi[7]),
          [x8]"v"(xi[8])
        : "s40","s41","s42","s43","s44","s45","s46","s47","s48","s49",
          "s50","s51","s52","s53","s54","s55","s56","s57","s58","s59",
          "s60","s61","s62","s63","s64","s65","s66","s67","s68","s69",
          "s70","s71",
          "v0","v1","v2","v3","v4","v5","v6","v7","v8","v9","v10","v11",
          "v12","v13","v14","v15","v16","v17","v18","v19",
          "vcc","scc","memory");

    // ---- cross-half reduction (plain HIP: compiler owns LDS/barriers) ----
    if (half) {
#pragma unroll
        for (int t = 0; t < 13; ++t)
            red[t * 128 + el] = acc[t];
    }
    __syncthreads();
    if (!half) {
#pragma unroll
        for (int t = 0; t < 13; ++t) {
            f32x2 r = red[t * 128 + el];
            acc[t].x += r.x; acc[t].y += r.y;
        }
    }
    __syncthreads();
    if (half) {
#pragma unroll
        for (int t = 13; t < 25; ++t)
            red[(t - 13) * 128 + el] = acc[t];
    }
    __syncthreads();
    if (!half) {
#pragma unroll
        for (int t = 13; t < 25; ++t) {
            f32x2 r = red[(t - 13) * 128 + el];
            acc[t].x += r.x; acc[t].y += r.y;
        }
        // ---- phase 2: output LIF + coalesced float2 stores ----
        const float b20 = b2[0], b21 = b2[1];
        float2* __restrict__ out_spk = (float2*)out;
        float2* __restrict__ out_mem = (float2*)(out + (size_t)T * BATCH * NO);
        float m0 = 0.0f, m1 = 0.0f, s0 = 0.0f, s1 = 0.0f;
#pragma unroll
        for (int t = 0; t < T; ++t) {
            const float c0 = acc[t].x + b20;
            const float c1 = acc[t].y + b21;
            m0 = fmaf(0.95f, m0, c0) - s0;
            m1 = fmaf(0.95f, m1, c1) - s1;
            s0 = (m0 > 1.0f) ? 1.0f : 0.0f;
            s1 = (m1 > 1.0f) ? 1.0f : 0.0f;
            out_spk[(size_t)t * BATCH + e] = make_float2(s0, s1);
            out_mem[(size_t)t * BATCH + e] = make_float2(m0, m1);
        }
    }
}

extern "C" void kernel_launch(void* const* d_in, const int* in_sizes, int n_in,
                              void* d_out, int out_size, void* d_ws, size_t ws_size,
                              hipStream_t stream) {
    const float* x  = (const float*)d_in[0];
    const float* W1 = (const float*)d_in[1];
    const float* b1 = (const float*)d_in[2];
    const float* W2 = (const float*)d_in[3];
    const float* b2 = (const float*)d_in[4];
    float* out = (float*)d_out;

    dim3 block(256);
    dim3 grid(BATCH * 2 / 256);   // 2 threads per element
    snn_fwd<<<grid, block, 0, stream>>>(x, W1, b1, W2, b2, out);
}

// Round 2
// 155.904 us; speedup vs baseline: 1.1569x; 1.1569x over previous
//
#include <hip/hip_runtime.h>

#define BATCH 262144
#define NI 9
#define NH 100
#define NO 2
#define T 25

// R12 = R10 structure (scalar ops, per-h never-spike skip, VGPR-only TSTEP,
// HIP reduction/phase2) with the spike computation fused via the VOP3
// `clamp` modifier:
//   old: pre = v_fma(K, mem, -K);  spk = v_med3(pre, 0, 1)     [2 slots]
//   new: spk = v_fma(K, mem, -K) clamp                          [1 slot]
// Bit-identical: pre is quantized to {0} U (-inf,-2^36] U [2^37,inf) (ULP of
// mem near 1 is 2^-23, scaled by K=2^60), so clamp-to-[0,1] == med3 == the
// exact Heaviside (mem>1). Also specializes step 0 (mem=0,spk=0 -> mem=c),
// killing the 2 zero-init movs. Per-h slots 166 -> 140.
//
// R11 lesson (counter-verified): v_pk_fma_f32 costs 2 issue slots on gfx950
// (half-rate packed fp32); time tracks VALU slot count at ~3.05 cyc/slot
// (m07 ceiling). So optimization == slot reduction, nothing else matters
// until ~75 us.
// Predicted: dispatch 95.2 -> ~73-77 us; WRITE_SIZE unchanged; absmax
// unchanged (bit-identical math vs R10).

#define TSTEP(t) \
  "v_fma_f32 v1, v4, v1, v0\n\t" \
  "v_fmac_f32 v1, -1.0, v2\n\t" \
  "v_fma_f32 v2, v5, v1, -v5 clamp\n\t" \
  "v_fmac_f32 %[a" #t "x], v6, v2\n\t" \
  "v_fmac_f32 %[a" #t "y], v7, v2\n\t"

__global__
__attribute__((amdgpu_flat_work_group_size(256, 256), amdgpu_waves_per_eu(6, 8)))
void snn_fwd(
    const float* __restrict__ x,
    const float* __restrict__ W1,
    const float* __restrict__ b1,
    const float* __restrict__ W2,
    const float* __restrict__ b2,
    float* __restrict__ out)
{
    __shared__ float2 red[13 * 128];   // 13 t-slots x 128 elems = 13312 B

    const int tid  = threadIdx.x;
    const int lane = tid & 63;
    const int w    = tid >> 6;
    const int half = __builtin_amdgcn_readfirstlane(w & 1);  // wave-uniform
    const int el   = (w >> 1) * 64 + lane;                   // 0..127
    const int e    = blockIdx.x * 128 + el;

    float xi[NI];
#pragma unroll
    for (int i = 0; i < NI; ++i) xi[i] = x[(size_t)e * NI + i];

    float acc0[T], acc1[T];
#pragma unroll
    for (int t = 0; t < T; ++t) { acc0[t] = 0.0f; acc1[t] = 0.0f; }

    // Uniform (SGPR) h-partition pointers.
    const float* W1h = W1 + half * 50 * NI;
    const float* b1h = b1 + half * 50;
    const float* W2h = W2 + half * 50;   // W2[1,h] at byte offset +0x190

    asm volatile(
        "s_mov_b64 s[40:41], %[pw1]\n\t"
        "s_mov_b64 s[42:43], %[pb1]\n\t"
        "s_mov_b64 s[44:45], %[pw2]\n\t"
        "v_mov_b32 v4, 0x3f733333\n\t"    // beta = 0.95f
        "v_mov_b32 v5, 0x5d800000\n\t"    // K = 2^60
        "s_mov_b32 s62, 50\n\t"           // h counter
        "s_load_dwordx8 s[48:55], s[40:41], 0x0\n\t"
        "s_load_dword s56, s[40:41], 0x20\n\t"
        "s_load_dword s57, s[42:43], 0x0\n\t"
        "s_load_dword s58, s[44:45], 0x0\n\t"
        "s_load_dword s59, s[44:45], 0x190\n\t"
        "1:\n\t"
        "s_waitcnt lgkmcnt(0)\n\t"
        "v_mov_b32 v6, s58\n\t"           // w0 -> VGPR (TSTEP is VGPR-only)
        "v_mov_b32 v7, s59\n\t"           // w1
        "v_mul_f32 v0, s48, %[x0]\n\t"
        "v_fma_f32 v0, s49, %[x1], v0\n\t"
        "v_fma_f32 v0, s50, %[x2], v0\n\t"
        "v_fma_f32 v0, s51, %[x3], v0\n\t"
        "v_fma_f32 v0, s52, %[x4], v0\n\t"
        "v_fma_f32 v0, s53, %[x5], v0\n\t"
        "v_fma_f32 v0, s54, %[x6], v0\n\t"
        "v_fma_f32 v0, s55, %[x7], v0\n\t"
        "v_fma_f32 v0, s56, %[x8], v0\n\t"
        "v_add_f32 v0, s57, v0\n\t"
        // prefetch next h's weights (skip on last iteration)
        "s_cmp_lg_u32 s62, 1\n\t"
        "s_cbranch_scc0 2f\n\t"
        "s_add_u32 s40, s40, 36\n\t"
        "s_addc_u32 s41, s41, 0\n\t"
        "s_add_u32 s42, s42, 4\n\t"
        "s_addc_u32 s43, s43, 0\n\t"
        "s_add_u32 s44, s44, 4\n\t"
        "s_addc_u32 s45, s45, 0\n\t"
        "s_load_dwordx8 s[48:55], s[40:41], 0x0\n\t"
        "s_load_dword s56, s[40:41], 0x20\n\t"
        "s_load_dword s57, s[42:43], 0x0\n\t"
        "s_load_dword s58, s[44:45], 0x0\n\t"
        "s_load_dword s59, s[44:45], 0x190\n\t"
        "2:\n\t"
        // never-spike skip (exact 25-step bound): no lane with c > 0.0625
        "v_cmp_lt_f32 vcc, 0x3d800000, v0\n\t"
        "s_cbranch_vccz 3f\n\t"
        // step 0 specialized: mem = beta*0 + c - 0 = c
        "v_mov_b32 v1, v0\n\t"
        "v_fma_f32 v2, v5, v1, -v5 clamp\n\t"
        "v_fmac_f32 %[a0x], v6, v2\n\t"
        "v_fmac_f32 %[a0y], v7, v2\n\t"
        TSTEP(1)  TSTEP(2)  TSTEP(3)  TSTEP(4)
        TSTEP(5)  TSTEP(6)  TSTEP(7)  TSTEP(8)  TSTEP(9)
        TSTEP(10) TSTEP(11) TSTEP(12) TSTEP(13) TSTEP(14)
        TSTEP(15) TSTEP(16) TSTEP(17) TSTEP(18) TSTEP(19)
        TSTEP(20) TSTEP(21) TSTEP(22) TSTEP(23) TSTEP(24)
        "3:\n\t"
        "s_sub_u32 s62, s62, 1\n\t"
        "s_cmp_lg_u32 s62, 0\n\t"
        "s_cbranch_scc1 1b\n\t"
        : [a0x]"+v"(acc0[0]),  [a0y]"+v"(acc1[0]),
          [a1x]"+v"(acc0[1]),  [a1y]"+v"(acc1[1]),
          [a2x]"+v"(acc0[2]),  [a2y]"+v"(acc1[2]),
          [a3x]"+v"(acc0[3]),  [a3y]"+v"(acc1[3]),
          [a4x]"+v"(acc0[4]),  [a4y]"+v"(acc1[4]),
          [a5x]"+v"(acc0[5]),  [a5y]"+v"(acc1[5]),
          [a6x]"+v"(acc0[6]),  [a6y]"+v"(acc1[6]),
          [a7x]"+v"(acc0[7]),  [a7y]"+v"(acc1[7]),
          [a8x]"+v"(acc0[8]),  [a8y]"+v"(acc1[8]),
          [a9x]"+v"(acc0[9]),  [a9y]"+v"(acc1[9]),
          [a10x]"+v"(acc0[10]), [a10y]"+v"(acc1[10]),
          [a11x]"+v"(acc0[11]), [a11y]"+v"(acc1[11]),
          [a12x]"+v"(acc0[12]), [a12y]"+v"(acc1[12]),
          [a13x]"+v"(acc0[13]), [a13y]"+v"(acc1[13]),
          [a14x]"+v"(acc0[14]), [a14y]"+v"(acc1[14]),
          [a15x]"+v"(acc0[15]), [a15y]"+v"(acc1[15]),
          [a16x]"+v"(acc0[16]), [a16y]"+v"(acc1[16]),
          [a17x]"+v"(acc0[17]), [a17y]"+v"(acc1[17]),
          [a18x]"+v"(acc0[18]), [a18y]"+v"(acc1[18]),
          [a19x]"+v"(acc0[19]), [a19y]"+v"(acc1[19]),
          [a20x]"+v"(acc0[20]), [a20y]"+v"(acc1[20]),
          [a21x]"+v"(acc0[21]), [a21y]"+v"(acc1[21]),
          [a22x]"+v"(acc0[22]), [a22y]"+v"(acc1[22]),
          [a23x]"+v"(acc0[23]), [a23y]"+v"(acc1[23]),
          [a24x]"+v"(acc0[24]), [a24y]"+v"(acc1[24])
        : [pw1]"s"(W1h), [pb1]"s"(b1h), [pw2]"s"(W2h),
          [x0]"v"(xi[0]), [x1]"v"(xi[1]), [x2]"v"(xi[2]), [x3]"v"(xi[3]),
          [x4]"v"(xi[4]), [x5]"v"(xi[5]), [x6]"v"(xi[6]), [x7]"v"(xi[7]),
          [x8]"v"(xi[8])
        : "s40","s41","s42","s43","s44","s45","s46","s47","s48","s49",
          "s50","s51","s52","s53","s54","s55","s56","s57","s58","s59",
          "s60","s61","s62",
          "v0","v1","v2","v3","v4","v5","v6","v7",
          "vcc","scc","memory");

    // ---- cross-half reduction (plain HIP: compiler owns LDS/barriers) ----
    if (half) {
#pragma unroll
        for (int t = 0; t < 13; ++t)
            red[t * 128 + el] = make_float2(acc0[t], acc1[t]);
    }
    __syncthreads();
    if (!half) {
#pragma unroll
        for (int t = 0; t < 13; ++t) {
            float2 r = red[t * 128 + el];
            acc0[t] += r.x; acc1[t] += r.y;
        }
    }
    __syncthreads();
    if (half) {
#pragma unroll
        for (int t = 13; t < 25; ++t)
            red[(t - 13) * 128 + el] = make_float2(acc0[t], acc1[t]);
    }
    __syncthreads();
    if (!half) {
#pragma unroll
        for (int t = 13; t < 25; ++t) {
            float2 r = red[(t - 13) * 128 + el];
            acc0[t] += r.x; acc1[t] += r.y;
        }
        // ---- phase 2: output LIF + coalesced float2 stores ----
        const float b20 = b2[0], b21 = b2[1];
        float2* __restrict__ out_spk = (float2*)out;
        float2* __restrict__ out_mem = (float2*)(out + (size_t)T * BATCH * NO);
        float m0 = 0.0f, m1 = 0.0f, s0 = 0.0f, s1 = 0.0f;
#pragma unroll
        for (int t = 0; t < T; ++t) {
            const float c0 = acc0[t] + b20;
            const float c1 = acc1[t] + b21;
            m0 = fmaf(0.95f, m0, c0) - s0;
            m1 = fmaf(0.95f, m1, c1) - s1;
            s0 = (m0 > 1.0f) ? 1.0f : 0.0f;
            s1 = (m1 > 1.0f) ? 1.0f : 0.0f;
            out_spk[(size_t)t * BATCH + e] = make_float2(s0, s1);
            out_mem[(size_t)t * BATCH + e] = make_float2(m0, m1);
        }
    }
}

extern "C" void kernel_launch(void* const* d_in, const int* in_sizes, int n_in,
                              void* d_out, int out_size, void* d_ws, size_t ws_size,
                              hipStream_t stream) {
    const float* x  = (const float*)d_in[0];
    const float* W1 = (const float*)d_in[1];
    const float* b1 = (const float*)d_in[2];
    const float* W2 = (const float*)d_in[3];
    const float* b2 = (const float*)d_in[4];
    float* out = (float*)d_out;

    dim3 block(256);
    dim3 grid(BATCH * 2 / 256);   // 2 threads per element
    snn_fwd<<<grid, block, 0, stream>>>(x, W1, b1, W2, b2, out);
}